// Round 1
// baseline (847.998 us; speedup 1.0000x reference)
//
#include <hip/hip_runtime.h>

// GCN tail: 2×(GCNConv+ReLU) + linear head.
// N=100000, E=1000000, F_in=128, H=64, C=40 (sizes derived at runtime).
//
// Pipeline (all fp32):
//   deg[i] = 1 + #(dst==i);  dinv = rsqrt(deg)
//   bufA = x @ W1
//   bufB = selfloop_init(bufA, dinv)  (= bufA * dinv^2, also serves as zero-init)
//   bufB[dst] += bufA[src] * dinv[src]*dinv[dst]   (atomic scatter, 64 lanes/edge)
//   bufB = relu(bufB + b1)
//   bufA = bufB @ W2 ; repeat aggregation ; bufB = relu(bufB + b2)
//   out  = bufB @ Wc + bc

#ifndef __HIP_DEVICE_COMPILE__
#endif

__device__ __forceinline__ float atomic_add_f32(float* addr, float v) {
#if defined(__AMDGCN__) || defined(__HIP_DEVICE_COMPILE__)
    return unsafeAtomicAdd(addr, v);   // hardware global_atomic_add_f32
#else
    return atomicAdd(addr, v);
#endif
}

__global__ void deg_init_kernel(float* __restrict__ deg, int N) {
    int i = blockIdx.x * blockDim.x + threadIdx.x;
    if (i < N) deg[i] = 1.0f;   // self-loop
}

__global__ void deg_count_kernel(const int* __restrict__ dst, float* __restrict__ deg, int E) {
    int e = blockIdx.x * blockDim.x + threadIdx.x;
    if (e < E) atomic_add_f32(&deg[dst[e]], 1.0f);
}

__global__ void dinv_kernel(float* __restrict__ deg, int N) {
    int i = blockIdx.x * blockDim.x + threadIdx.x;
    if (i < N) deg[i] = rsqrtf(deg[i]);   // deg >= 1 always (self-loop)
}

// out[M,64] = A[M,K] @ W[K,64].  W staged in LDS.  16 rows/block, 4 rows/thread.
// Requires M % 16 == 0 handled by guard (full 4-row groups only; M=100000 is 16-divisible).
template <int K>
__global__ __launch_bounds__(256) void gemm_n64(const float* __restrict__ A,
                                                const float* __restrict__ W,
                                                float* __restrict__ out, int M) {
    __shared__ float lw[K * 64];
    for (int i = threadIdx.x; i < K * 64; i += 256) lw[i] = W[i];
    __syncthreads();
    const int col  = threadIdx.x & 63;
    const int rg   = threadIdx.x >> 6;
    const int row0 = blockIdx.x * 16 + rg * 4;
    if (row0 + 3 >= M) {
        if (row0 >= M) return;
    }
    const float* __restrict__ a0 = A + (size_t)row0 * K;
    const float* __restrict__ a1 = a0 + K;
    const float* __restrict__ a2 = a1 + K;
    const float* __restrict__ a3 = a2 + K;
    float acc0 = 0.f, acc1 = 0.f, acc2 = 0.f, acc3 = 0.f;
#pragma unroll
    for (int k = 0; k < K; k += 4) {
        float4 va0 = *(const float4*)(a0 + k);
        float4 va1 = *(const float4*)(a1 + k);
        float4 va2 = *(const float4*)(a2 + k);
        float4 va3 = *(const float4*)(a3 + k);
        float w0 = lw[(k + 0) * 64 + col];
        float w1 = lw[(k + 1) * 64 + col];
        float w2 = lw[(k + 2) * 64 + col];
        float w3 = lw[(k + 3) * 64 + col];
        acc0 += va0.x * w0 + va0.y * w1 + va0.z * w2 + va0.w * w3;
        acc1 += va1.x * w0 + va1.y * w1 + va1.z * w2 + va1.w * w3;
        acc2 += va2.x * w0 + va2.y * w1 + va2.z * w2 + va2.w * w3;
        acc3 += va3.x * w0 + va3.y * w1 + va3.z * w2 + va3.w * w3;
    }
    out[(size_t)(row0 + 0) * 64 + col] = acc0;
    out[(size_t)(row0 + 1) * 64 + col] = acc1;
    out[(size_t)(row0 + 2) * 64 + col] = acc2;
    out[(size_t)(row0 + 3) * 64 + col] = acc3;
}

// bufB[i][c] = bufA[i][c] * dinv[i]^2   (self-loop term; also the zero-init)
__global__ void selfloop_init_kernel(const float* __restrict__ h,
                                     const float* __restrict__ dinv,
                                     float* __restrict__ out, int total) {
    int i = blockIdx.x * blockDim.x + threadIdx.x;
    if (i < total) {
        float di = dinv[i >> 6];
        out[i] = h[i] * di * di;
    }
}

// One edge per 64-lane wave; lane = feature column.
__global__ __launch_bounds__(256) void scatter_edges_kernel(const int* __restrict__ src,
                                                            const int* __restrict__ dst,
                                                            const float* __restrict__ dinv,
                                                            const float* __restrict__ h,
                                                            float* __restrict__ out, int E) {
    int e = blockIdx.x * 4 + (threadIdx.x >> 6);
    int c = threadIdx.x & 63;
    if (e >= E) return;
    int s = src[e];
    int d = dst[e];
    float nrm = dinv[s] * dinv[d];
    float v = h[(size_t)s * 64 + c] * nrm;
    atomic_add_f32(&out[(size_t)d * 64 + c], v);
}

__global__ void bias_relu_kernel(float* __restrict__ x, const float* __restrict__ b, int total) {
    int i = blockIdx.x * blockDim.x + threadIdx.x;
    if (i < total) {
        float v = x[i] + b[i & 63];
        x[i] = v > 0.f ? v : 0.f;
    }
}

// out[M,40] = A[M,64] @ W[64,40] + bias.  W padded to 64 cols in LDS.
__global__ __launch_bounds__(256) void gemm_out_kernel(const float* __restrict__ A,
                                                       const float* __restrict__ W,
                                                       const float* __restrict__ bias,
                                                       float* __restrict__ out, int M) {
    __shared__ float lw[64 * 64];
    for (int i = threadIdx.x; i < 64 * 64; i += 256) {
        int k = i >> 6, c = i & 63;
        lw[i] = (c < 40) ? W[k * 40 + c] : 0.f;
    }
    __syncthreads();
    const int col  = threadIdx.x & 63;
    const int rg   = threadIdx.x >> 6;
    const int row0 = blockIdx.x * 16 + rg * 4;
    if (row0 >= M) return;
    const float* __restrict__ a0 = A + (size_t)row0 * 64;
    const float* __restrict__ a1 = a0 + 64;
    const float* __restrict__ a2 = a1 + 64;
    const float* __restrict__ a3 = a2 + 64;
    float acc0 = 0.f, acc1 = 0.f, acc2 = 0.f, acc3 = 0.f;
#pragma unroll
    for (int k = 0; k < 64; k += 4) {
        float4 va0 = *(const float4*)(a0 + k);
        float4 va1 = *(const float4*)(a1 + k);
        float4 va2 = *(const float4*)(a2 + k);
        float4 va3 = *(const float4*)(a3 + k);
        float w0 = lw[(k + 0) * 64 + col];
        float w1 = lw[(k + 1) * 64 + col];
        float w2 = lw[(k + 2) * 64 + col];
        float w3 = lw[(k + 3) * 64 + col];
        acc0 += va0.x * w0 + va0.y * w1 + va0.z * w2 + va0.w * w3;
        acc1 += va1.x * w0 + va1.y * w1 + va1.z * w2 + va1.w * w3;
        acc2 += va2.x * w0 + va2.y * w1 + va2.z * w2 + va2.w * w3;
        acc3 += va3.x * w0 + va3.y * w1 + va3.z * w2 + va3.w * w3;
    }
    if (col < 40) {
        float bb = bias[col];
        out[(size_t)(row0 + 0) * 40 + col] = acc0 + bb;
        out[(size_t)(row0 + 1) * 40 + col] = acc1 + bb;
        out[(size_t)(row0 + 2) * 40 + col] = acc2 + bb;
        out[(size_t)(row0 + 3) * 40 + col] = acc3 + bb;
    }
}

extern "C" void kernel_launch(void* const* d_in, const int* in_sizes, int n_in,
                              void* d_out, int out_size, void* d_ws, size_t ws_size,
                              hipStream_t stream) {
    const float* x  = (const float*)d_in[0];
    const int*   ei = (const int*)d_in[1];
    const float* W1 = (const float*)d_in[2];
    const float* b1 = (const float*)d_in[3];
    const float* W2 = (const float*)d_in[4];
    const float* b2 = (const float*)d_in[5];
    const float* Wc = (const float*)d_in[6];
    const float* bc = (const float*)d_in[7];

    const int N = in_sizes[0] / 128;   // 100000
    const int E = in_sizes[1] / 2;     // 1000000
    const int* src = ei;
    const int* dst = ei + E;

    float* ws   = (float*)d_ws;
    float* dinv = ws;                                   // N floats
    float* bufA = ws + (((size_t)N + 127) & ~(size_t)127);  // N*64 floats
    float* bufB = bufA + (size_t)N * 64;                // N*64 floats

    const int total = N * 64;
    dim3 blk(256);
    int nblkN  = (N + 255) / 256;
    int nblkE  = (E + 255) / 256;
    int nblkT  = (total + 255) / 256;
    int nblkG  = (N + 15) / 16;       // gemm blocks (16 rows each)
    int nblkS  = (E + 3) / 4;         // scatter blocks (4 edges each)

    // degree / dinv
    deg_init_kernel<<<nblkN, blk, 0, stream>>>(dinv, N);
    deg_count_kernel<<<nblkE, blk, 0, stream>>>(dst, dinv, E);
    dinv_kernel<<<nblkN, blk, 0, stream>>>(dinv, N);

    // layer 1
    gemm_n64<128><<<nblkG, blk, 0, stream>>>(x, W1, bufA, N);
    selfloop_init_kernel<<<nblkT, blk, 0, stream>>>(bufA, dinv, bufB, total);
    scatter_edges_kernel<<<nblkS, blk, 0, stream>>>(src, dst, dinv, bufA, bufB, E);
    bias_relu_kernel<<<nblkT, blk, 0, stream>>>(bufB, b1, total);

    // layer 2
    gemm_n64<64><<<nblkG, blk, 0, stream>>>(bufB, W2, bufA, N);
    selfloop_init_kernel<<<nblkT, blk, 0, stream>>>(bufA, dinv, bufB, total);
    scatter_edges_kernel<<<nblkS, blk, 0, stream>>>(src, dst, dinv, bufA, bufB, E);
    bias_relu_kernel<<<nblkT, blk, 0, stream>>>(bufB, b2, total);

    // head
    gemm_out_kernel<<<nblkG, blk, 0, stream>>>(bufB, Wc, bc, (float*)d_out, N);
}

// Round 2
// 563.230 us; speedup vs baseline: 1.5056x; 1.5056x over previous
//
#include <hip/hip_runtime.h>

// GCN tail: 2×(GCNConv+ReLU) + linear head.  N=100000, E=1000000, F_in=128, H=64, C=40.
//
// R2: CSR-gather aggregation (no f32 atomics, single write per dst row),
// fused selfloop+bias+relu into the gather kernel.
//
// Pipeline (all fp32):
//   counts[i] = indeg(i)                (int histogram)
//   dinv[i]   = rsqrt(counts[i]+1)      (+1 self-loop)
//   offsets   = exclusive_scan(counts)  (3-kernel scan)
//   adj       = CSR fill via cursor atomics (cursor[i] ends at offsets[i+1])
//   bufA = x @ W1
//   bufB[i] = relu(dinv[i]*(bufA[i]*dinv[i] + sum_{s in adj[i]} bufA[s]*dinv[s]) + b1)
//   bufA = bufB @ W2 ; repeat gather with b2 ; out = bufB @ Wc + bc

__global__ void zero_counts_kernel(int* __restrict__ counts, int N) {
    int i = blockIdx.x * blockDim.x + threadIdx.x;
    if (i < N) counts[i] = 0;
}

__global__ void hist_kernel(const int* __restrict__ dst, int* __restrict__ counts, int E) {
    int e = blockIdx.x * blockDim.x + threadIdx.x;
    if (e < E) atomicAdd(&counts[dst[e]], 1);
}

__global__ void dinv_kernel(const int* __restrict__ counts, float* __restrict__ dinv, int N) {
    int i = blockIdx.x * blockDim.x + threadIdx.x;
    if (i < N) dinv[i] = rsqrtf((float)(counts[i] + 1));
}

// ---- exclusive scan of counts[N] -> offsets[N], 1024 items per block ----
__global__ __launch_bounds__(256) void scanA_kernel(const int* __restrict__ counts,
                                                    int* __restrict__ offsets,
                                                    int* __restrict__ blockSums, int N) {
    __shared__ int tmp[256];
    const int t  = threadIdx.x;
    const int i0 = blockIdx.x * 1024 + t * 4;
    int c0 = (i0 + 0 < N) ? counts[i0 + 0] : 0;
    int c1 = (i0 + 1 < N) ? counts[i0 + 1] : 0;
    int c2 = (i0 + 2 < N) ? counts[i0 + 2] : 0;
    int c3 = (i0 + 3 < N) ? counts[i0 + 3] : 0;
    int s = c0 + c1 + c2 + c3;
    tmp[t] = s;
    __syncthreads();
    for (int off = 1; off < 256; off <<= 1) {
        int v = (t >= off) ? tmp[t - off] : 0;
        __syncthreads();
        tmp[t] += v;
        __syncthreads();
    }
    int excl = tmp[t] - s;
    if (t == 255) blockSums[blockIdx.x] = tmp[255];
    if (i0 + 0 < N) offsets[i0 + 0] = excl;
    if (i0 + 1 < N) offsets[i0 + 1] = excl + c0;
    if (i0 + 2 < N) offsets[i0 + 2] = excl + c0 + c1;
    if (i0 + 3 < N) offsets[i0 + 3] = excl + c0 + c1 + c2;
}

// exclusive scan of blockSums[B] in-place (B <= 1024)
__global__ __launch_bounds__(256) void scanB_kernel(int* __restrict__ blockSums, int B) {
    __shared__ int tmp[1024];
    const int t = threadIdx.x;
    for (int i = t; i < B; i += 256) tmp[i] = blockSums[i];
    __syncthreads();
    if (t == 0) {
        int run = 0;
        for (int i = 0; i < B; ++i) { int v = tmp[i]; tmp[i] = run; run += v; }
    }
    __syncthreads();
    for (int i = t; i < B; i += 256) blockSums[i] = tmp[i];
}

__global__ void scanC_kernel(int* __restrict__ offsets, int* __restrict__ cursor,
                             const int* __restrict__ blockSums, int N) {
    int i = blockIdx.x * blockDim.x + threadIdx.x;
    if (i < N) {
        int v = offsets[i] + blockSums[i >> 10];
        offsets[i] = v;
        cursor[i]  = v;   // fill bumps this to offsets[i+1]
    }
}

__global__ void fill_kernel(const int* __restrict__ src, const int* __restrict__ dst,
                            int* __restrict__ cursor, int* __restrict__ adj, int E) {
    int e = blockIdx.x * blockDim.x + threadIdx.x;
    if (e < E) {
        int pos = atomicAdd(&cursor[dst[e]], 1);
        adj[pos] = src[e];
    }
}

// out[M,64] = A[M,K] @ W[K,64].  W staged in LDS.  16 rows/block, 4 rows/thread.
template <int K>
__global__ __launch_bounds__(256) void gemm_n64(const float* __restrict__ A,
                                                const float* __restrict__ W,
                                                float* __restrict__ out, int M) {
    __shared__ float lw[K * 64];
    for (int i = threadIdx.x; i < K * 64; i += 256) lw[i] = W[i];
    __syncthreads();
    const int col  = threadIdx.x & 63;
    const int rg   = threadIdx.x >> 6;
    const int row0 = blockIdx.x * 16 + rg * 4;
    if (row0 >= M) return;
    const float* __restrict__ a0 = A + (size_t)row0 * K;
    const float* __restrict__ a1 = a0 + K;
    const float* __restrict__ a2 = a1 + K;
    const float* __restrict__ a3 = a2 + K;
    float acc0 = 0.f, acc1 = 0.f, acc2 = 0.f, acc3 = 0.f;
#pragma unroll
    for (int k = 0; k < K; k += 4) {
        float4 va0 = *(const float4*)(a0 + k);
        float4 va1 = *(const float4*)(a1 + k);
        float4 va2 = *(const float4*)(a2 + k);
        float4 va3 = *(const float4*)(a3 + k);
        float w0 = lw[(k + 0) * 64 + col];
        float w1 = lw[(k + 1) * 64 + col];
        float w2 = lw[(k + 2) * 64 + col];
        float w3 = lw[(k + 3) * 64 + col];
        acc0 += va0.x * w0 + va0.y * w1 + va0.z * w2 + va0.w * w3;
        acc1 += va1.x * w0 + va1.y * w1 + va1.z * w2 + va1.w * w3;
        acc2 += va2.x * w0 + va2.y * w1 + va2.z * w2 + va2.w * w3;
        acc3 += va3.x * w0 + va3.y * w1 + va3.z * w2 + va3.w * w3;
    }
    out[(size_t)(row0 + 0) * 64 + col] = acc0;
    out[(size_t)(row0 + 1) * 64 + col] = acc1;
    out[(size_t)(row0 + 2) * 64 + col] = acc2;
    out[(size_t)(row0 + 3) * 64 + col] = acc3;
}

// Fused: out[i] = relu(dinv[i]*(h[i]*dinv[i] + sum_{s} h[s]*dinv[s]) + b)
// One 64-lane wave per node; lane = feature column. Edge indices chunked 64
// at a time into lanes, broadcast via shfl.
__global__ __launch_bounds__(256) void gather_kernel(const float* __restrict__ h,
                                                     const int* __restrict__ offsets,
                                                     const int* __restrict__ cursor,
                                                     const int* __restrict__ adj,
                                                     const float* __restrict__ dinv,
                                                     const float* __restrict__ bias,
                                                     float* __restrict__ out, int N) {
    const int node = blockIdx.x * 4 + (threadIdx.x >> 6);
    const int c    = threadIdx.x & 63;
    if (node >= N) return;
    const int start = offsets[node];
    const int end   = cursor[node];   // == offsets[node+1] after fill
    const float di  = dinv[node];
    float acc = h[(size_t)node * 64 + c] * di;   // self-loop (× di again at end)
    for (int base = start; base < end; base += 64) {
        const int m = min(64, end - base);
        int   sidx = 0;
        float sw   = 0.f;
        if (c < m) {
            sidx = adj[base + c];
            sw   = dinv[sidx];
        }
        for (int j = 0; j < m; ++j) {
            int   s = __shfl(sidx, j);
            float w = __shfl(sw, j);
            acc += h[(size_t)s * 64 + c] * w;
        }
    }
    float v = acc * di + bias[c];
    out[(size_t)node * 64 + c] = v > 0.f ? v : 0.f;
}

// out[M,40] = A[M,64] @ W[64,40] + bias.  W padded to 64 cols in LDS.
__global__ __launch_bounds__(256) void gemm_out_kernel(const float* __restrict__ A,
                                                       const float* __restrict__ W,
                                                       const float* __restrict__ bias,
                                                       float* __restrict__ out, int M) {
    __shared__ float lw[64 * 64];
    for (int i = threadIdx.x; i < 64 * 64; i += 256) {
        int k = i >> 6, c = i & 63;
        lw[i] = (c < 40) ? W[k * 40 + c] : 0.f;
    }
    __syncthreads();
    const int col  = threadIdx.x & 63;
    const int rg   = threadIdx.x >> 6;
    const int row0 = blockIdx.x * 16 + rg * 4;
    if (row0 >= M) return;
    const float* __restrict__ a0 = A + (size_t)row0 * 64;
    const float* __restrict__ a1 = a0 + 64;
    const float* __restrict__ a2 = a1 + 64;
    const float* __restrict__ a3 = a2 + 64;
    float acc0 = 0.f, acc1 = 0.f, acc2 = 0.f, acc3 = 0.f;
#pragma unroll
    for (int k = 0; k < 64; k += 4) {
        float4 va0 = *(const float4*)(a0 + k);
        float4 va1 = *(const float4*)(a1 + k);
        float4 va2 = *(const float4*)(a2 + k);
        float4 va3 = *(const float4*)(a3 + k);
        float w0 = lw[(k + 0) * 64 + col];
        float w1 = lw[(k + 1) * 64 + col];
        float w2 = lw[(k + 2) * 64 + col];
        float w3 = lw[(k + 3) * 64 + col];
        acc0 += va0.x * w0 + va0.y * w1 + va0.z * w2 + va0.w * w3;
        acc1 += va1.x * w0 + va1.y * w1 + va1.z * w2 + va1.w * w3;
        acc2 += va2.x * w0 + va2.y * w1 + va2.z * w2 + va2.w * w3;
        acc3 += va3.x * w0 + va3.y * w1 + va3.z * w2 + va3.w * w3;
    }
    if (col < 40) {
        float bb = bias[col];
        out[(size_t)(row0 + 0) * 40 + col] = acc0 + bb;
        out[(size_t)(row0 + 1) * 40 + col] = acc1 + bb;
        out[(size_t)(row0 + 2) * 40 + col] = acc2 + bb;
        out[(size_t)(row0 + 3) * 40 + col] = acc3 + bb;
    }
}

extern "C" void kernel_launch(void* const* d_in, const int* in_sizes, int n_in,
                              void* d_out, int out_size, void* d_ws, size_t ws_size,
                              hipStream_t stream) {
    const float* x  = (const float*)d_in[0];
    const int*   ei = (const int*)d_in[1];
    const float* W1 = (const float*)d_in[2];
    const float* b1 = (const float*)d_in[3];
    const float* W2 = (const float*)d_in[4];
    const float* b2 = (const float*)d_in[5];
    const float* Wc = (const float*)d_in[6];
    const float* bc = (const float*)d_in[7];

    const int N = in_sizes[0] / 128;   // 100000
    const int E = in_sizes[1] / 2;     // 1000000
    const int* src = ei;
    const int* dst = ei + E;

    // workspace carve-up (256 B aligned)
    char* w = (char*)d_ws;
    auto alloc = [&](size_t bytes) { char* p = w; w += (bytes + 255) & ~(size_t)255; return p; };
    int*   counts    = (int*)alloc((size_t)N * 4);
    int*   offsets   = (int*)alloc(((size_t)N + 1) * 4);
    int*   cursor    = (int*)alloc((size_t)N * 4);
    int*   blockSums = (int*)alloc(1024 * 4);
    int*   adj       = (int*)alloc((size_t)E * 4);
    float* dinv      = (float*)alloc((size_t)N * 4);
    float* bufA      = (float*)alloc((size_t)N * 64 * 4);
    float* bufB      = (float*)alloc((size_t)N * 64 * 4);

    dim3 blk(256);
    const int nblkN = (N + 255) / 256;
    const int nblkE = (E + 255) / 256;
    const int nblkG = (N + 15) / 16;     // gemm blocks (16 rows each)
    const int nblkV = (N + 3) / 4;       // gather blocks (4 nodes each)
    const int B     = (N + 1023) / 1024; // scan blocks

    // ---- CSR build + dinv ----
    zero_counts_kernel<<<nblkN, blk, 0, stream>>>(counts, N);
    hist_kernel<<<nblkE, blk, 0, stream>>>(dst, counts, E);
    dinv_kernel<<<nblkN, blk, 0, stream>>>(counts, dinv, N);
    scanA_kernel<<<B, blk, 0, stream>>>(counts, offsets, blockSums, N);
    scanB_kernel<<<1, blk, 0, stream>>>(blockSums, B);
    scanC_kernel<<<nblkN, blk, 0, stream>>>(offsets, cursor, blockSums, N);
    fill_kernel<<<nblkE, blk, 0, stream>>>(src, dst, cursor, adj, E);

    // ---- layer 1 ----
    gemm_n64<128><<<nblkG, blk, 0, stream>>>(x, W1, bufA, N);
    gather_kernel<<<nblkV, blk, 0, stream>>>(bufA, offsets, cursor, adj, dinv, b1, bufB, N);

    // ---- layer 2 ----
    gemm_n64<64><<<nblkG, blk, 0, stream>>>(bufB, W2, bufA, N);
    gather_kernel<<<nblkV, blk, 0, stream>>>(bufA, offsets, cursor, adj, dinv, b2, bufB, N);

    // ---- head ----
    gemm_out_kernel<<<nblkG, blk, 0, stream>>>(bufB, Wc, bc, (float*)d_out, N);
}

// Round 3
// 414.354 us; speedup vs baseline: 2.0466x; 1.3593x over previous
//
#include <hip/hip_runtime.h>

// GCN tail: 2×(GCNConv+ReLU) + linear head.  N=100000, E=1000000, F_in=128, H=64, C=40.
//
// R3: LDS-tiled fp32 GEMM (64-row tile, 4x4 register blocking, padded-stride
// LDS to kill bank conflicts). R1's GEMM was L1-bound: every A-load was
// wave-uniform -> 64x redundant L1 traffic (VALUBusy 26%, HBM 5%).
//
// Pipeline (all fp32):
//   CSR build (hist -> scan -> cursor fill) + dinv = rsqrt(deg+1)
//   bufA = x @ W1            (gemm_tiled<128,64,false>)
//   bufB = gather(bufA)      (fused selfloop+bias+relu, no atomics)
//   bufA = bufB @ W2         (gemm_tiled<64,64,false>)
//   bufB = gather(bufA)
//   out  = bufB @ Wc + bc    (gemm_tiled<64,40,true>)

__global__ void zero_counts_kernel(int* __restrict__ counts, int N) {
    int i = blockIdx.x * blockDim.x + threadIdx.x;
    if (i < N) counts[i] = 0;
}

__global__ void hist_kernel(const int* __restrict__ dst, int* __restrict__ counts, int E) {
    int e = blockIdx.x * blockDim.x + threadIdx.x;
    if (e < E) atomicAdd(&counts[dst[e]], 1);
}

__global__ void dinv_kernel(const int* __restrict__ counts, float* __restrict__ dinv, int N) {
    int i = blockIdx.x * blockDim.x + threadIdx.x;
    if (i < N) dinv[i] = rsqrtf((float)(counts[i] + 1));
}

// ---- exclusive scan of counts[N] -> offsets[N], 1024 items per block ----
__global__ __launch_bounds__(256) void scanA_kernel(const int* __restrict__ counts,
                                                    int* __restrict__ offsets,
                                                    int* __restrict__ blockSums, int N) {
    __shared__ int tmp[256];
    const int t  = threadIdx.x;
    const int i0 = blockIdx.x * 1024 + t * 4;
    int c0 = (i0 + 0 < N) ? counts[i0 + 0] : 0;
    int c1 = (i0 + 1 < N) ? counts[i0 + 1] : 0;
    int c2 = (i0 + 2 < N) ? counts[i0 + 2] : 0;
    int c3 = (i0 + 3 < N) ? counts[i0 + 3] : 0;
    int s = c0 + c1 + c2 + c3;
    tmp[t] = s;
    __syncthreads();
    for (int off = 1; off < 256; off <<= 1) {
        int v = (t >= off) ? tmp[t - off] : 0;
        __syncthreads();
        tmp[t] += v;
        __syncthreads();
    }
    int excl = tmp[t] - s;
    if (t == 255) blockSums[blockIdx.x] = tmp[255];
    if (i0 + 0 < N) offsets[i0 + 0] = excl;
    if (i0 + 1 < N) offsets[i0 + 1] = excl + c0;
    if (i0 + 2 < N) offsets[i0 + 2] = excl + c0 + c1;
    if (i0 + 3 < N) offsets[i0 + 3] = excl + c0 + c1 + c2;
}

__global__ __launch_bounds__(256) void scanB_kernel(int* __restrict__ blockSums, int B) {
    __shared__ int tmp[1024];
    const int t = threadIdx.x;
    for (int i = t; i < B; i += 256) tmp[i] = blockSums[i];
    __syncthreads();
    if (t == 0) {
        int run = 0;
        for (int i = 0; i < B; ++i) { int v = tmp[i]; tmp[i] = run; run += v; }
    }
    __syncthreads();
    for (int i = t; i < B; i += 256) blockSums[i] = tmp[i];
}

__global__ void scanC_kernel(int* __restrict__ offsets, int* __restrict__ cursor,
                             const int* __restrict__ blockSums, int N) {
    int i = blockIdx.x * blockDim.x + threadIdx.x;
    if (i < N) {
        int v = offsets[i] + blockSums[i >> 10];
        offsets[i] = v;
        cursor[i]  = v;
    }
}

__global__ void fill_kernel(const int* __restrict__ src, const int* __restrict__ dst,
                            int* __restrict__ cursor, int* __restrict__ adj, int E) {
    int e = blockIdx.x * blockDim.x + threadIdx.x;
    if (e < E) {
        int pos = atomicAdd(&cursor[dst[e]], 1);
        adj[pos] = src[e];
    }
}

// ---- LDS-tiled GEMM: out[M,NOUT] = A[M,K] @ W[K,NOUT] (+bias) --------------
// 256 threads, 64 rows/block, 4x4 register tile per thread.
// A staged in 64-k stages, LDS row stride 66 (a-reads hit banks {0,8,16,24}).
template <int K, int NOUT, bool BIAS>
__global__ __launch_bounds__(256) void gemm_tiled(const float* __restrict__ A,
                                                  const float* __restrict__ W,
                                                  const float* __restrict__ bias,
                                                  float* __restrict__ out, int M) {
    constexpr int KS  = 64;
    constexpr int NST = K / KS;
    __shared__ float At[64 * 66];
    __shared__ float Wt[K * 64];

    // stage W (zero-pad cols to 64 when NOUT<64)
    for (int i = threadIdx.x; i < K * 64; i += 256) {
        if (NOUT == 64) {
            Wt[i] = W[i];
        } else {
            int k = i >> 6, c = i & 63;
            Wt[i] = (c < NOUT) ? W[k * NOUT + c] : 0.f;
        }
    }

    const int tc   = threadIdx.x & 15;   // col group: cols tc*4..+3
    const int tr   = threadIdx.x >> 4;   // row group: rows tr*4..+3
    const int row0 = blockIdx.x * 64;

    float acc[4][4] = {};

    for (int st = 0; st < NST; ++st) {
        __syncthreads();   // Wt ready (st==0) / At reads of prev stage done
        // stage A[row0..row0+64, st*KS..+KS)
        int g = threadIdx.x;
#pragma unroll
        for (int i = 0; i < 4; ++i, g += 256) {
            int r  = g >> 4;
            int kc = (g & 15) << 2;
            int grow = row0 + r;
            if (grow > M - 1) grow = M - 1;
            float4 v = *(const float4*)(A + (size_t)grow * K + st * KS + kc);
            float* p = &At[r * 66 + kc];
            p[0] = v.x; p[1] = v.y; p[2] = v.z; p[3] = v.w;
        }
        __syncthreads();

        const float* a0p = &At[(tr * 4 + 0) * 66];
        const float* a1p = &At[(tr * 4 + 1) * 66];
        const float* a2p = &At[(tr * 4 + 2) * 66];
        const float* a3p = &At[(tr * 4 + 3) * 66];
        const float* wp  = &Wt[st * KS * 64 + tc * 4];
#pragma unroll 8
        for (int k = 0; k < KS; ++k) {
            float a0 = a0p[k];
            float a1 = a1p[k];
            float a2 = a2p[k];
            float a3 = a3p[k];
            float4 w = *(const float4*)(wp + k * 64);
            acc[0][0] += a0 * w.x; acc[0][1] += a0 * w.y; acc[0][2] += a0 * w.z; acc[0][3] += a0 * w.w;
            acc[1][0] += a1 * w.x; acc[1][1] += a1 * w.y; acc[1][2] += a1 * w.z; acc[1][3] += a1 * w.w;
            acc[2][0] += a2 * w.x; acc[2][1] += a2 * w.y; acc[2][2] += a2 * w.z; acc[2][3] += a2 * w.w;
            acc[3][0] += a3 * w.x; acc[3][1] += a3 * w.y; acc[3][2] += a3 * w.z; acc[3][3] += a3 * w.w;
        }
    }

    // epilogue: 4 float4 stores (guarded)
    if (NOUT < 64 && tc * 4 >= NOUT) return;
    float4 bb = {0.f, 0.f, 0.f, 0.f};
    if (BIAS) bb = *(const float4*)(bias + tc * 4);
#pragma unroll
    for (int j = 0; j < 4; ++j) {
        int row = row0 + tr * 4 + j;
        if (row >= M) break;
        float4 v;
        v.x = acc[j][0] + bb.x;
        v.y = acc[j][1] + bb.y;
        v.z = acc[j][2] + bb.z;
        v.w = acc[j][3] + bb.w;
        *(float4*)(out + (size_t)row * NOUT + tc * 4) = v;
    }
}

// Fused: out[i] = relu(dinv[i]*(h[i]*dinv[i] + sum_s h[s]*dinv[s]) + b)
// One 64-lane wave per node; lane = feature column.
__global__ __launch_bounds__(256) void gather_kernel(const float* __restrict__ h,
                                                     const int* __restrict__ offsets,
                                                     const int* __restrict__ cursor,
                                                     const int* __restrict__ adj,
                                                     const float* __restrict__ dinv,
                                                     const float* __restrict__ bias,
                                                     float* __restrict__ out, int N) {
    const int node = blockIdx.x * 4 + (threadIdx.x >> 6);
    const int c    = threadIdx.x & 63;
    if (node >= N) return;
    const int start = offsets[node];
    const int end   = cursor[node];
    const float di  = dinv[node];
    float acc = h[(size_t)node * 64 + c] * di;
    for (int base = start; base < end; base += 64) {
        const int m = min(64, end - base);
        int   sidx = 0;
        float sw   = 0.f;
        if (c < m) {
            sidx = adj[base + c];
            sw   = dinv[sidx];
        }
        for (int j = 0; j < m; ++j) {
            int   s = __shfl(sidx, j);
            float w = __shfl(sw, j);
            acc += h[(size_t)s * 64 + c] * w;
        }
    }
    float v = acc * di + bias[c];
    out[(size_t)node * 64 + c] = v > 0.f ? v : 0.f;
}

extern "C" void kernel_launch(void* const* d_in, const int* in_sizes, int n_in,
                              void* d_out, int out_size, void* d_ws, size_t ws_size,
                              hipStream_t stream) {
    const float* x  = (const float*)d_in[0];
    const int*   ei = (const int*)d_in[1];
    const float* W1 = (const float*)d_in[2];
    const float* b1 = (const float*)d_in[3];
    const float* W2 = (const float*)d_in[4];
    const float* b2 = (const float*)d_in[5];
    const float* Wc = (const float*)d_in[6];
    const float* bc = (const float*)d_in[7];

    const int N = in_sizes[0] / 128;   // 100000
    const int E = in_sizes[1] / 2;     // 1000000
    const int* src = ei;
    const int* dst = ei + E;

    char* w = (char*)d_ws;
    auto alloc = [&](size_t bytes) { char* p = w; w += (bytes + 255) & ~(size_t)255; return p; };
    int*   counts    = (int*)alloc((size_t)N * 4);
    int*   offsets   = (int*)alloc(((size_t)N + 1) * 4);
    int*   cursor    = (int*)alloc((size_t)N * 4);
    int*   blockSums = (int*)alloc(1024 * 4);
    int*   adj       = (int*)alloc((size_t)E * 4);
    float* dinv      = (float*)alloc((size_t)N * 4);
    float* bufA      = (float*)alloc((size_t)N * 64 * 4);
    float* bufB      = (float*)alloc((size_t)N * 64 * 4);

    dim3 blk(256);
    const int nblkN = (N + 255) / 256;
    const int nblkE = (E + 255) / 256;
    const int nblkG = (N + 63) / 64;     // tiled gemm blocks (64 rows each)
    const int nblkV = (N + 3) / 4;       // gather blocks (4 nodes each)
    const int B     = (N + 1023) / 1024; // scan blocks

    // ---- CSR build + dinv ----
    zero_counts_kernel<<<nblkN, blk, 0, stream>>>(counts, N);
    hist_kernel<<<nblkE, blk, 0, stream>>>(dst, counts, E);
    dinv_kernel<<<nblkN, blk, 0, stream>>>(counts, dinv, N);
    scanA_kernel<<<B, blk, 0, stream>>>(counts, offsets, blockSums, N);
    scanB_kernel<<<1, blk, 0, stream>>>(blockSums, B);
    scanC_kernel<<<nblkN, blk, 0, stream>>>(offsets, cursor, blockSums, N);
    fill_kernel<<<nblkE, blk, 0, stream>>>(src, dst, cursor, adj, E);

    // ---- layer 1 ----
    gemm_tiled<128, 64, false><<<nblkG, blk, 0, stream>>>(x, W1, nullptr, bufA, N);
    gather_kernel<<<nblkV, blk, 0, stream>>>(bufA, offsets, cursor, adj, dinv, b1, bufB, N);

    // ---- layer 2 ----
    gemm_tiled<64, 64, false><<<nblkG, blk, 0, stream>>>(bufB, W2, nullptr, bufA, N);
    gather_kernel<<<nblkV, blk, 0, stream>>>(bufA, offsets, cursor, adj, dinv, b2, bufB, N);

    // ---- head ----
    gemm_tiled<64, 40, true><<<nblkG, blk, 0, stream>>>(bufB, Wc, bc, (float*)d_out, N);
}

// Round 4
// 402.560 us; speedup vs baseline: 2.1065x; 1.0293x over previous
//
#include <hip/hip_runtime.h>
#include <hip/hip_fp16.h>

// GCN tail: 2×(GCNConv+ReLU) + linear head.  N=100000, E=1000000, F_in=128, H=64, C=40.
//
// R4: fp16 intermediate h buffers (halves gather row traffic, fp32 accum) and
// (src, dinv[src]) packed int2 adjacency (kills 1M random 4-B dinv gathers
// per gather dispatch). R3 gathers were gather-BW bound: FETCH 130 MB,
// VALUBusy 22%.
//
// Pipeline:
//   CSR build (hist -> scan -> cursor fill w/ packed weights) + dinv
//   bufA(h16) = x @ W1                    gemm<128,64, A=f32, O=f16>
//   bufB(h16) = gather(bufA)+bias+relu    (fp32 accum)
//   bufA(h16) = bufB @ W2                 gemm<64,64,  A=f16, O=f16>
//   bufB(h16) = gather(bufA)+bias+relu
//   out(f32)  = bufB @ Wc + bc            gemm<64,40,  A=f16, O=f32>

union H8 { uint4 u; __half h[8]; };
union H4 { uint2 u; __half h[4]; };

__global__ void zero_counts_kernel(int* __restrict__ counts, int N) {
    int i = blockIdx.x * blockDim.x + threadIdx.x;
    if (i < N) counts[i] = 0;
}

__global__ void hist_kernel(const int* __restrict__ dst, int* __restrict__ counts, int E) {
    int e = blockIdx.x * blockDim.x + threadIdx.x;
    if (e < E) atomicAdd(&counts[dst[e]], 1);
}

__global__ void dinv_kernel(const int* __restrict__ counts, float* __restrict__ dinv, int N) {
    int i = blockIdx.x * blockDim.x + threadIdx.x;
    if (i < N) dinv[i] = rsqrtf((float)(counts[i] + 1));
}

// ---- exclusive scan of counts[N] -> offsets[N], 1024 items per block ----
__global__ __launch_bounds__(256) void scanA_kernel(const int* __restrict__ counts,
                                                    int* __restrict__ offsets,
                                                    int* __restrict__ blockSums, int N) {
    __shared__ int tmp[256];
    const int t  = threadIdx.x;
    const int i0 = blockIdx.x * 1024 + t * 4;
    int c0 = (i0 + 0 < N) ? counts[i0 + 0] : 0;
    int c1 = (i0 + 1 < N) ? counts[i0 + 1] : 0;
    int c2 = (i0 + 2 < N) ? counts[i0 + 2] : 0;
    int c3 = (i0 + 3 < N) ? counts[i0 + 3] : 0;
    int s = c0 + c1 + c2 + c3;
    tmp[t] = s;
    __syncthreads();
    for (int off = 1; off < 256; off <<= 1) {
        int v = (t >= off) ? tmp[t - off] : 0;
        __syncthreads();
        tmp[t] += v;
        __syncthreads();
    }
    int excl = tmp[t] - s;
    if (t == 255) blockSums[blockIdx.x] = tmp[255];
    if (i0 + 0 < N) offsets[i0 + 0] = excl;
    if (i0 + 1 < N) offsets[i0 + 1] = excl + c0;
    if (i0 + 2 < N) offsets[i0 + 2] = excl + c0 + c1;
    if (i0 + 3 < N) offsets[i0 + 3] = excl + c0 + c1 + c2;
}

__global__ __launch_bounds__(256) void scanB_kernel(int* __restrict__ blockSums, int B) {
    __shared__ int tmp[1024];
    const int t = threadIdx.x;
    for (int i = t; i < B; i += 256) tmp[i] = blockSums[i];
    __syncthreads();
    if (t == 0) {
        int run = 0;
        for (int i = 0; i < B; ++i) { int v = tmp[i]; tmp[i] = run; run += v; }
    }
    __syncthreads();
    for (int i = t; i < B; i += 256) blockSums[i] = tmp[i];
}

__global__ void scanC_kernel(int* __restrict__ offsets, int* __restrict__ cursor,
                             const int* __restrict__ blockSums, int N) {
    int i = blockIdx.x * blockDim.x + threadIdx.x;
    if (i < N) {
        int v = offsets[i] + blockSums[i >> 10];
        offsets[i] = v;
        cursor[i]  = v;
    }
}

// adj entry = (src, bits(dinv[src])) — weight fetched once here instead of
// per-gather random scalar loads.
__global__ void fill_kernel(const int* __restrict__ src, const int* __restrict__ dst,
                            const float* __restrict__ dinv,
                            int* __restrict__ cursor, int2* __restrict__ adj, int E) {
    int e = blockIdx.x * blockDim.x + threadIdx.x;
    if (e < E) {
        int s = src[e];
        int pos = atomicAdd(&cursor[dst[e]], 1);
        adj[pos] = make_int2(s, __float_as_int(dinv[s]));
    }
}

// ---- LDS-tiled GEMM: out[M,NOUT] = A[M,K] @ W[K,NOUT] (+bias) --------------
// 256 threads, 64 rows/block, 4x4 register tile per thread.
// At stride 66 -> conflict-free LDS reads. A/out dtype templated (fp32/fp16).
template <int K, int NOUT, bool BIAS, bool AHALF, bool OHALF>
__global__ __launch_bounds__(256) void gemm_tiled(const void* __restrict__ Av,
                                                  const float* __restrict__ W,
                                                  const float* __restrict__ bias,
                                                  void* __restrict__ outv, int M) {
    constexpr int KS  = 64;
    constexpr int NST = K / KS;
    __shared__ float At[64 * 66];
    __shared__ float Wt[K * 64];

    for (int i = threadIdx.x; i < K * 64; i += 256) {
        if (NOUT == 64) {
            Wt[i] = W[i];
        } else {
            int k = i >> 6, c = i & 63;
            Wt[i] = (c < NOUT) ? W[k * NOUT + c] : 0.f;
        }
    }

    const int tc   = threadIdx.x & 15;
    const int tr   = threadIdx.x >> 4;
    const int row0 = blockIdx.x * 64;

    float acc[4][4] = {};

    for (int st = 0; st < NST; ++st) {
        __syncthreads();
        if (AHALF) {
            const __half* Ah = (const __half*)Av;
            int g = threadIdx.x;
#pragma unroll
            for (int i = 0; i < 2; ++i, g += 256) {
                int r  = g >> 3;
                int kc = (g & 7) << 3;
                int grow = row0 + r;
                if (grow > M - 1) grow = M - 1;
                H8 v;
                v.u = *(const uint4*)(Ah + (size_t)grow * K + st * KS + kc);
                float* p = &At[r * 66 + kc];
#pragma unroll
                for (int j = 0; j < 8; ++j) p[j] = __half2float(v.h[j]);
            }
        } else {
            const float* Af = (const float*)Av;
            int g = threadIdx.x;
#pragma unroll
            for (int i = 0; i < 4; ++i, g += 256) {
                int r  = g >> 4;
                int kc = (g & 15) << 2;
                int grow = row0 + r;
                if (grow > M - 1) grow = M - 1;
                float4 v = *(const float4*)(Af + (size_t)grow * K + st * KS + kc);
                float* p = &At[r * 66 + kc];
                p[0] = v.x; p[1] = v.y; p[2] = v.z; p[3] = v.w;
            }
        }
        __syncthreads();

        const float* a0p = &At[(tr * 4 + 0) * 66];
        const float* a1p = &At[(tr * 4 + 1) * 66];
        const float* a2p = &At[(tr * 4 + 2) * 66];
        const float* a3p = &At[(tr * 4 + 3) * 66];
        const float* wp  = &Wt[st * KS * 64 + tc * 4];
#pragma unroll 8
        for (int k = 0; k < KS; ++k) {
            float a0 = a0p[k];
            float a1 = a1p[k];
            float a2 = a2p[k];
            float a3 = a3p[k];
            float4 w = *(const float4*)(wp + k * 64);
            acc[0][0] += a0 * w.x; acc[0][1] += a0 * w.y; acc[0][2] += a0 * w.z; acc[0][3] += a0 * w.w;
            acc[1][0] += a1 * w.x; acc[1][1] += a1 * w.y; acc[1][2] += a1 * w.z; acc[1][3] += a1 * w.w;
            acc[2][0] += a2 * w.x; acc[2][1] += a2 * w.y; acc[2][2] += a2 * w.z; acc[2][3] += a2 * w.w;
            acc[3][0] += a3 * w.x; acc[3][1] += a3 * w.y; acc[3][2] += a3 * w.z; acc[3][3] += a3 * w.w;
        }
    }

    if (NOUT < 64 && tc * 4 >= NOUT) return;
    float4 bb = {0.f, 0.f, 0.f, 0.f};
    if (BIAS) bb = *(const float4*)(bias + tc * 4);
#pragma unroll
    for (int j = 0; j < 4; ++j) {
        int row = row0 + tr * 4 + j;
        if (row >= M) break;
        float vx = acc[j][0] + bb.x;
        float vy = acc[j][1] + bb.y;
        float vz = acc[j][2] + bb.z;
        float vw = acc[j][3] + bb.w;
        if (OHALF) {
            __half* oh = (__half*)outv;
            H4 v;
            v.h[0] = __float2half(vx); v.h[1] = __float2half(vy);
            v.h[2] = __float2half(vz); v.h[3] = __float2half(vw);
            *(uint2*)(oh + (size_t)row * NOUT + tc * 4) = v.u;
        } else {
            float4 v = {vx, vy, vz, vw};
            *(float4*)((float*)outv + (size_t)row * NOUT + tc * 4) = v;
        }
    }
}

// Fused: out[i] = relu(dinv[i]*(h[i]*dinv[i] + sum_s h[s]*w_s) + b), fp16 h.
// One 64-lane wave per node; lane = feature column.
__global__ __launch_bounds__(256) void gather_kernel(const __half* __restrict__ h,
                                                     const int* __restrict__ offsets,
                                                     const int* __restrict__ cursor,
                                                     const int2* __restrict__ adj,
                                                     const float* __restrict__ dinv,
                                                     const float* __restrict__ bias,
                                                     __half* __restrict__ out, int N) {
    const int node = blockIdx.x * 4 + (threadIdx.x >> 6);
    const int c    = threadIdx.x & 63;
    if (node >= N) return;
    const int start = offsets[node];
    const int end   = cursor[node];
    const float di  = dinv[node];
    float acc = __half2float(h[(size_t)node * 64 + c]) * di;
    for (int base = start; base < end; base += 64) {
        const int m = min(64, end - base);
        int   sidx = 0;
        float sw   = 0.f;
        if (c < m) {
            int2 pr = adj[base + c];
            sidx = pr.x;
            sw   = __int_as_float(pr.y);
        }
        for (int j = 0; j < m; ++j) {
            int   s = __shfl(sidx, j);
            float w = __shfl(sw, j);
            acc += __half2float(h[(size_t)s * 64 + c]) * w;
        }
    }
    float v = acc * di + bias[c];
    out[(size_t)node * 64 + c] = __float2half(v > 0.f ? v : 0.f);
}

extern "C" void kernel_launch(void* const* d_in, const int* in_sizes, int n_in,
                              void* d_out, int out_size, void* d_ws, size_t ws_size,
                              hipStream_t stream) {
    const float* x  = (const float*)d_in[0];
    const int*   ei = (const int*)d_in[1];
    const float* W1 = (const float*)d_in[2];
    const float* b1 = (const float*)d_in[3];
    const float* W2 = (const float*)d_in[4];
    const float* b2 = (const float*)d_in[5];
    const float* Wc = (const float*)d_in[6];
    const float* bc = (const float*)d_in[7];

    const int N = in_sizes[0] / 128;   // 100000
    const int E = in_sizes[1] / 2;     // 1000000
    const int* src = ei;
    const int* dst = ei + E;

    char* w = (char*)d_ws;
    auto alloc = [&](size_t bytes) { char* p = w; w += (bytes + 255) & ~(size_t)255; return p; };
    int*    counts    = (int*)alloc((size_t)N * 4);
    int*    offsets   = (int*)alloc(((size_t)N + 1) * 4);
    int*    cursor    = (int*)alloc((size_t)N * 4);
    int*    blockSums = (int*)alloc(1024 * 4);
    int2*   adj       = (int2*)alloc((size_t)E * 8);
    float*  dinv      = (float*)alloc((size_t)N * 4);
    __half* bufA      = (__half*)alloc((size_t)N * 64 * 2);
    __half* bufB      = (__half*)alloc((size_t)N * 64 * 2);

    dim3 blk(256);
    const int nblkN = (N + 255) / 256;
    const int nblkE = (E + 255) / 256;
    const int nblkG = (N + 63) / 64;
    const int nblkV = (N + 3) / 4;
    const int B     = (N + 1023) / 1024;

    // ---- CSR build + dinv ----
    zero_counts_kernel<<<nblkN, blk, 0, stream>>>(counts, N);
    hist_kernel<<<nblkE, blk, 0, stream>>>(dst, counts, E);
    dinv_kernel<<<nblkN, blk, 0, stream>>>(counts, dinv, N);
    scanA_kernel<<<B, blk, 0, stream>>>(counts, offsets, blockSums, N);
    scanB_kernel<<<1, blk, 0, stream>>>(blockSums, B);
    scanC_kernel<<<nblkN, blk, 0, stream>>>(offsets, cursor, blockSums, N);
    fill_kernel<<<nblkE, blk, 0, stream>>>(src, dst, dinv, cursor, adj, E);

    // ---- layer 1 ----
    gemm_tiled<128, 64, false, false, true><<<nblkG, blk, 0, stream>>>(x, W1, nullptr, bufA, N);
    gather_kernel<<<nblkV, blk, 0, stream>>>(bufA, offsets, cursor, adj, dinv, b1, bufB, N);

    // ---- layer 2 ----
    gemm_tiled<64, 64, false, true, true><<<nblkG, blk, 0, stream>>>(bufB, W2, nullptr, bufA, N);
    gather_kernel<<<nblkV, blk, 0, stream>>>(bufA, offsets, cursor, adj, dinv, b2, bufB, N);

    // ---- head ----
    gemm_tiled<64, 40, true, true, false><<<nblkG, blk, 0, stream>>>(bufB, Wc, bc, d_out, N);
}